// Round 8
// baseline (126.341 us; speedup 1.0000x reference)
//
#include <hip/hip_runtime.h>

// ============================================================================
// R8: occupancy experiment — BM 64 -> 16, 1024 blocks x 256 thr (4 waves),
// 4 blocks/CU (37 KB LDS, 128-VGPR cap), simple m97-style 2-barrier
// single-buffered loop (compiler-scheduled; m114 cross-block overlap hides
// the vmcnt(0) drains). Diagnosis R7: R2/R6/R7 (3 schedules, 2x traffic
// range) all ~30-31 us with all pipes <10% busy -> barrier-convoy latency
// with too few independent blocks/CU, not bandwidth. m97's 874-TF regime
// is 3-4 small blocks/CU; this reproduces it at our shape.
// ============================================================================

#define D_IN   1024
#define D_PROJ 256
#define N_C    64
#define N_ROWS 16384
#define BM     16
#define BK     64
#define BSZ (D_PROJ * BK)   // 16384 shorts = 32 KB B tile (single-buffered)
#define ATS 1024            // shorts per A tile (16 rows x 64 k, swizzled)
#define Z_STRIDE 264        // D_PROJ + 8 pad

typedef float v4f __attribute__((ext_vector_type(4)));
typedef short v8s __attribute__((ext_vector_type(8)));

__device__ inline unsigned short f2bf(float f) {
  unsigned int u = __float_as_uint(f);
  u = u + 0x7fffu + ((u >> 16) & 1u);   // round-to-nearest-even
  return (unsigned short)(u >> 16);
}

__device__ inline void async16(const void* g, void* s) {
  __builtin_amdgcn_global_load_lds(
      (const __attribute__((address_space(1))) unsigned int*)g,
      (__attribute__((address_space(3))) unsigned int*)s, 16, 0, 0);
}

// ---------------------------------------------------------------------------
// Prep (unchanged): projT bf16 [256][1024], protoB bf16 [64][256], pnorm2[64],
// mu_p[256] = mean @ proj
// ---------------------------------------------------------------------------
__global__ __launch_bounds__(256) void prep_kernel(
    const float* __restrict__ proj,      // [1024][256]
    const float* __restrict__ protos,    // [64][256]
    const float* __restrict__ mean,      // [1024]
    unsigned short* __restrict__ projT,  // [256][1024]
    unsigned short* __restrict__ protoB, // [64][256]
    float* __restrict__ pnorm2,          // [64]
    float* __restrict__ mu_p)            // [256]
{
  __shared__ float tile[64][65];
  __shared__ float part[16][17];
  const int b = blockIdx.x;
  const int t = threadIdx.x;
  if (b < 64) {
    const int k0 = (b & 15) * 64, n0 = (b >> 4) * 64;
    const int r = t >> 4, c4 = (t & 15) * 4;
    for (int rr = r; rr < 64; rr += 16) {
      const float4 v = *(const float4*)(proj + (k0 + rr) * D_PROJ + n0 + c4);
      tile[rr][c4 + 0] = v.x; tile[rr][c4 + 1] = v.y;
      tile[rr][c4 + 2] = v.z; tile[rr][c4 + 3] = v.w;
    }
    __syncthreads();
    const int n = t >> 2, kc = (t & 3) * 16;
    unsigned short o[16];
#pragma unroll
    for (int i = 0; i < 16; ++i) o[i] = f2bf(tile[kc + i][n]);
    unsigned short* dst = projT + (n0 + n) * D_IN + k0 + kc;
#pragma unroll
    for (int i = 0; i < 4; ++i) {
      ushort4 s4 = { o[4*i+0], o[4*i+1], o[4*i+2], o[4*i+3] };
      *(ushort4*)(dst + 4*i) = s4;
    }
  } else if (b < 80) {
    const int w = t >> 6, l = t & 63;
    const int c = (b - 64) * 4 + w;                    // proto 0..63
    const float4 v = *(const float4*)(protos + c * D_PROJ + l * 4);
    float ss = v.x*v.x + v.y*v.y + v.z*v.z + v.w*v.w;
#pragma unroll
    for (int m = 1; m < 64; m <<= 1) ss += __shfl_xor(ss, m);
    if (l == 0) pnorm2[c] = ss;
    ushort4 o = { f2bf(v.x), f2bf(v.y), f2bf(v.z), f2bf(v.w) };
    *(ushort4*)(protoB + c * D_PROJ + l * 4) = o;
  } else {
    const int b2  = b - 80;
    const int col = b2 * 16 + (t & 15);
    const int ks  = t >> 4;
    float s = 0.0f;
    const int kb = ks * 64;
#pragma unroll 4
    for (int k = 0; k < 64; ++k)
      s = fmaf(mean[kb + k], proj[(kb + k) * D_PROJ + col], s);
    part[ks][t & 15] = s;
    __syncthreads();
    if (t < 16) {
      float acc = 0.0f;
#pragma unroll
      for (int i = 0; i < 16; ++i) acc += part[i][t];
      mu_p[b2 * 16 + t] = acc;
    }
  }
}

// ---------------------------------------------------------------------------
// Main: 16 rows/block, 1024 blocks (4/CU), 256 threads (4 waves).
// Wave w owns rows 0..15 x cols w*64..w*64+63 (4 col-frags).
// Per tile kt: sync; stage B(kt) [8 DMA/thread-wave] + write A(kt);
//              sync (vmcnt0+lgkm drain — hidden by 3 other blocks, m114);
//              compute: 2 ksteps x (1 A + 4 B ds_read_b128 + 4 MFMA).
// X preloaded to registers in 4 chunks, converted bf16 ahead of use (R2 flow).
// ---------------------------------------------------------------------------
__global__ __launch_bounds__(256, 4) void protonet_main(
    const float* __restrict__ X,               // [16384][1024]
    const unsigned short* __restrict__ projT,  // [256][1024] bf16
    const unsigned short* __restrict__ protoB, // [64][256]   bf16
    const float* __restrict__ pnorm2,          // [64]
    const float* __restrict__ mu_p,            // [256]
    float* __restrict__ out)                   // [16384][64]
{
  __shared__ unsigned short lds_A[2 * ATS];   // 4 KB, double-buffered, swizzled
  __shared__ unsigned short lds_B[BSZ];       // 32 KB, single-buffered (Z alias)
  __shared__ float lds_part[4][BM];
  __shared__ float lds_inv[BM];
  __shared__ float lds_z2[BM];

  const int t  = threadIdx.x;
  const int w  = t >> 6;        // wave 0..3
  const int l  = t & 63;
  const int q  = l >> 4;
  const int lc = l & 15;
  const int row0 = blockIdx.x * BM;

  // B DMA src: instr s covers rows w*64+s*8 .. +7; lane l -> row +(l>>3);
  // phys chunk l&7 holds logical (l&7)^(row&7) via pre-swizzled source.
  const int bsrc0 = ((w << 6) + (l >> 3)) * D_IN + (((l & 7) ^ ((l >> 3) & 7)) << 3);

  // A staging: thread owns row ar (0..15), float4 slot aj (0..15) of the tile
  const int ar = t >> 4;
  const int aj = t & 15;
  const float* xbase = X + (row0 + ar) * D_IN + (aj << 2);
  unsigned short* awr = lds_A + (ar << 6) +
      ((((aj >> 1) ^ (ar & 7)) << 3) | ((aj & 1) << 2));

  ushort4 abf[16];     // bf16 A slices, one per k-tile (32 VGPRs)
  float4  xf[4];       // in-flight X chunk (16 VGPRs)
  v4f     acc1[4];     // col-frags w*64 + j*16

#pragma unroll
  for (int j = 0; j < 4; ++j) acc1[j] = (v4f)(0.0f);

#pragma unroll
  for (int i = 0; i < 4; ++i) xf[i] = *(const float4*)(xbase + i * BK);

#pragma unroll
  for (int ch = 0; ch < 4; ++ch) {
    // convert current chunk (waits its loads), then issue next chunk
#pragma unroll
    for (int i = 0; i < 4; ++i) {
      const float4 v = xf[i];
      ushort4 o = { f2bf(v.x), f2bf(v.y), f2bf(v.z), f2bf(v.w) };
      abf[ch * 4 + i] = o;
    }
    if (ch < 3) {
#pragma unroll
      for (int i = 0; i < 4; ++i)
        xf[i] = *(const float4*)(xbase + ((ch + 1) * 4 + i) * BK);
    }
#pragma unroll
    for (int k2 = 0; k2 < 4; ++k2) {
      const int kt = ch * 4 + k2;
      __syncthreads();                       // previous compute done with B/A
      // stage B(kt): 8 x 1KB DMA per wave (wave-uniform dst)
#pragma unroll
      for (int s = 0; s < 8; ++s)
        async16(projT + bsrc0 + s * (8 * D_IN) + kt * BK,
                lds_B + ((w << 6) + (s << 3)) * BK);
      // A(kt) from registers
      *(ushort4*)(awr + ((kt & 1) << 10)) = abf[kt];
      __syncthreads();                       // drains vmcnt (B) + lgkm (A)
      // compute: 2 ksteps x (1 A read + 4 B reads + 4 MFMA)
      const unsigned short* Ab = lds_A + ((kt & 1) << 10);
#pragma unroll
      for (int kk = 0; kk < 2; ++kk) {
        const int po = (((kk << 2) + q) ^ (lc & 7)) << 3;
        v8s a = *(const v8s*)(Ab + (lc << 6) + po);
#pragma unroll
        for (int j = 0; j < 4; ++j) {
          v8s b = *(const v8s*)(lds_B + ((w << 6) + (j << 4) + lc) * BK + po);
          acc1[j] = __builtin_amdgcn_mfma_f32_16x16x32_bf16(a, b, acc1[j], 0, 0, 0);
        }
      }
    }
  }

  __syncthreads();                          // all B reads done (Z aliases B)

  // ---- GEMM2 proto loads issued now: latency hides under the Z phase ----
  v8s pb[8];
  {
    const unsigned short* prow = protoB + ((w << 4) + lc) * D_PROJ + (q << 3);
#pragma unroll
    for (int kk = 0; kk < 8; ++kk)
      pb[kk] = *(const v8s*)(prow + (kk << 5));
  }

  // ---- Zc = Zraw - mu_p -> Z (aliases lds_B) + fp32 row norms ----
  unsigned short* lds_Z = lds_B;
  float mu[4];
#pragma unroll
  for (int j = 0; j < 4; ++j) mu[j] = mu_p[(w << 6) + (j << 4) + lc];
#pragma unroll
  for (int r = 0; r < 4; ++r) {
    const int row = (q << 2) + r;
    float s2 = 0.0f;
#pragma unroll
    for (int j = 0; j < 4; ++j) {
      const float v = acc1[j][r] - mu[j];
      s2 += v * v;
      lds_Z[row * Z_STRIDE + (w << 6) + (j << 4) + lc] = f2bf(v);
    }
    s2 += __shfl_xor(s2, 1);
    s2 += __shfl_xor(s2, 2);
    s2 += __shfl_xor(s2, 4);
    s2 += __shfl_xor(s2, 8);
    if (lc == 0) lds_part[w][row] = s2;
  }
  __syncthreads();
  if (t < BM) {
    const float n2 = lds_part[0][t] + lds_part[1][t] + lds_part[2][t] + lds_part[3][t];
    const float nrm = sqrtf(n2);
    const float inv = 1.0f / fmaxf(nrm, 1e-12f);   // torch/jax normalize eps
    lds_inv[t] = inv;
    lds_z2[t]  = n2 * inv * inv;                   // == 1 unless degenerate
  }
  __syncthreads();

  // ---- GEMM2: dot(Zc, proto_c); wave w: 16 rows x protos w*16..+15 ----
  v4f acc2 = (v4f)(0.0f);
#pragma unroll
  for (int kk = 0; kk < 8; ++kk) {
    v8s za = *(const v8s*)(lds_Z + lc * Z_STRIDE + (kk << 5) + (q << 3));
    acc2 = __builtin_amdgcn_mfma_f32_16x16x32_bf16(za, pb[kk], acc2, 0, 0, 0);
  }

  // ---- epilogue: d^2 = ||Z||^2 + ||p||^2 - 2*dot*inv ; score = -sqrt(d^2) ----
  const int c  = (w << 4) + lc;
  const float pn = pnorm2[c];
#pragma unroll
  for (int r = 0; r < 4; ++r) {
    const int row = (q << 2) + r;
    const float inv = lds_inv[row];
    const float d2  = lds_z2[row] + pn - 2.0f * acc2[r] * inv;
    out[(row0 + row) * N_C + c] = -sqrtf(fmaxf(d2, 0.0f));
  }
}

extern "C" void kernel_launch(void* const* d_in, const int* in_sizes, int n_in,
                              void* d_out, int out_size, void* d_ws, size_t ws_size,
                              hipStream_t stream) {
  const float* X      = (const float*)d_in[0];
  const float* protos = (const float*)d_in[1];
  const float* mean   = (const float*)d_in[2];
  const float* proj   = (const float*)d_in[3];
  float* out = (float*)d_out;

  unsigned short* projT  = (unsigned short*)d_ws;          // 256*1024 bf16 = 512 KB
  unsigned short* protoB = projT + D_PROJ * D_IN;          // 64*256  bf16 = 32 KB
  float*          pn2    = (float*)(protoB + N_C * D_PROJ);// 64 fp32
  float*          mup    = pn2 + N_C;                      // 256 fp32

  prep_kernel<<<96, 256, 0, stream>>>(proj, protos, mean, projT, protoB, pn2, mup);
  protonet_main<<<N_ROWS / BM, 256, 0, stream>>>(X, projT, protoB, pn2, mup, out);
}

// Round 9
// 114.730 us; speedup vs baseline: 1.1012x; 1.1012x over previous
//
#include <hip/hip_runtime.h>

// ============================================================================
// R9: BARRIER-FREE k-loop. Diagnosis R8 (direct counters): MfmaUtil 7%,
// VALU 10%, HBM 12%, conflicts low, 31-44 us across 4 schedules -> the
// 2-barriers-per-tile convoy is the floor. Here each wave's B slice is
// wave-private (cols w*64..+63), so B needs NO barrier: per-wave 2-deep
// DMA pipeline with wave-local counted s_waitcnt vmcnt(16/8), never 0
// until tile 15 (AITER pattern). Only A (shared, 4-tile groups) keeps
// 2 lgkm-only barriers per group = 8 total vs R8's 32 full drains.
// LDS exactly 80 KB -> 2 blocks/CU; 4 waves/block free-running.
// ============================================================================

#define D_IN   1024
#define D_PROJ 256
#define N_C    64
#define N_ROWS 16384
#define BM     32
#define BK     64
#define Z_STRIDE 264        // D_PROJ + 8 pad

typedef float v4f __attribute__((ext_vector_type(4)));
typedef short v8s __attribute__((ext_vector_type(8)));

__device__ inline unsigned short f2bf(float f) {
  unsigned int u = __float_as_uint(f);
  u = u + 0x7fffu + ((u >> 16) & 1u);   // round-to-nearest-even
  return (unsigned short)(u >> 16);
}

__device__ inline void async16(const void* g, void* s) {
  __builtin_amdgcn_global_load_lds(
      (const __attribute__((address_space(1))) unsigned int*)g,
      (__attribute__((address_space(3))) unsigned int*)s, 16, 0, 0);
}

// lgkm-only barrier (A-group handoff): never drains vmcnt -> B DMAs live on
#define GBAR() do {                                              \
  asm volatile("s_waitcnt lgkmcnt(0)" ::: "memory");             \
  __builtin_amdgcn_s_barrier();                                  \
  __builtin_amdgcn_sched_barrier(0);                             \
} while (0)

// ---------------------------------------------------------------------------
// Prep (unchanged): projT bf16 [256][1024], protoB bf16 [64][256], pnorm2[64],
// mu_p[256] = mean @ proj
// ---------------------------------------------------------------------------
__global__ __launch_bounds__(256) void prep_kernel(
    const float* __restrict__ proj,      // [1024][256]
    const float* __restrict__ protos,    // [64][256]
    const float* __restrict__ mean,      // [1024]
    unsigned short* __restrict__ projT,  // [256][1024]
    unsigned short* __restrict__ protoB, // [64][256]
    float* __restrict__ pnorm2,          // [64]
    float* __restrict__ mu_p)            // [256]
{
  __shared__ float tile[64][65];
  __shared__ float part[16][17];
  const int b = blockIdx.x;
  const int t = threadIdx.x;
  if (b < 64) {
    const int k0 = (b & 15) * 64, n0 = (b >> 4) * 64;
    const int r = t >> 4, c4 = (t & 15) * 4;
    for (int rr = r; rr < 64; rr += 16) {
      const float4 v = *(const float4*)(proj + (k0 + rr) * D_PROJ + n0 + c4);
      tile[rr][c4 + 0] = v.x; tile[rr][c4 + 1] = v.y;
      tile[rr][c4 + 2] = v.z; tile[rr][c4 + 3] = v.w;
    }
    __syncthreads();
    const int n = t >> 2, kc = (t & 3) * 16;
    unsigned short o[16];
#pragma unroll
    for (int i = 0; i < 16; ++i) o[i] = f2bf(tile[kc + i][n]);
    unsigned short* dst = projT + (n0 + n) * D_IN + k0 + kc;
#pragma unroll
    for (int i = 0; i < 4; ++i) {
      ushort4 s4 = { o[4*i+0], o[4*i+1], o[4*i+2], o[4*i+3] };
      *(ushort4*)(dst + 4*i) = s4;
    }
  } else if (b < 80) {
    const int w = t >> 6, l = t & 63;
    const int c = (b - 64) * 4 + w;                    // proto 0..63
    const float4 v = *(const float4*)(protos + c * D_PROJ + l * 4);
    float ss = v.x*v.x + v.y*v.y + v.z*v.z + v.w*v.w;
#pragma unroll
    for (int m = 1; m < 64; m <<= 1) ss += __shfl_xor(ss, m);
    if (l == 0) pnorm2[c] = ss;
    ushort4 o = { f2bf(v.x), f2bf(v.y), f2bf(v.z), f2bf(v.w) };
    *(ushort4*)(protoB + c * D_PROJ + l * 4) = o;
  } else {
    const int b2  = b - 80;
    const int col = b2 * 16 + (t & 15);
    const int ks  = t >> 4;
    float s = 0.0f;
    const int kb = ks * 64;
#pragma unroll 4
    for (int k = 0; k < 64; ++k)
      s = fmaf(mean[kb + k], proj[(kb + k) * D_PROJ + col], s);
    part[ks][t & 15] = s;
    __syncthreads();
    if (t < 16) {
      float acc = 0.0f;
#pragma unroll
      for (int i = 0; i < 16; ++i) acc += part[i][t];
      mu_p[b2 * 16 + t] = acc;
    }
  }
}

// ---------------------------------------------------------------------------
// Main: 32 rows/block, 512 blocks (2/CU), 256 threads (4 free-running waves).
// Wave w: all 32 rows x cols w*64..+63. B staged wave-private, double-buffered
// (2x8KB quarters of the 2x32KB lds_B). vmcnt ledger (per wave, 8 ops/DMA
// batch, X-group = 8 loads issued one group ahead):
//   prologue: X(g0) B(0) B(1) X(g1) -> tiles 0,1: vm16; 2,3: vm8
//   each tile T issues B(T+2); group end: GBAR, cvt+write A, GBAR, X(g+2)
//   tiles 4,5,8,9: vm16; 6,7,10,11,12,13,14: vm8; 15: vm0
// ---------------------------------------------------------------------------
__global__ __launch_bounds__(256, 2) void protonet_main(
    const float* __restrict__ X,               // [16384][1024]
    const unsigned short* __restrict__ projT,  // [256][1024] bf16
    const unsigned short* __restrict__ protoB, // [64][256]   bf16
    const float* __restrict__ pnorm2,          // [64]
    const float* __restrict__ mu_p,            // [256]
    float* __restrict__ out)                   // [16384][64]
{
  __shared__ unsigned short lds_B[32768];   // 64 KB: 2 bufs x 4 wave-quarters(8KB)
  __shared__ unsigned short lds_A[8192];    // 16 KB: 4 k-tiles, swizzled
  // norm scratch aliases lds_A (dead after k-loop; written post-GBAR)
  float* lds_part = (float*)lds_A;          // [4][32]
  float* lds_inv  = (float*)lds_A + 128;    // [32]
  float* lds_z2   = (float*)lds_A + 160;    // [32]

  const int t  = threadIdx.x;
  const int w  = t >> 6;        // wave 0..3
  const int l  = t & 63;
  const int q  = l >> 4;
  const int lc = l & 15;
  const int row0 = blockIdx.x * BM;

  // B DMA src: instr s covers projT rows w*64+s*8..+7; lane l -> +(l>>3);
  // phys chunk l&7 holds logical (l&7)^(row&7) via pre-swizzled source.
  const int bsrc0 = ((w << 6) + (l >> 3)) * D_IN + (((l & 7) ^ ((l >> 3) & 7)) << 3);

  // A staging: thread owns row ar (0..31), chunk aj (0..7) = 8 floats/tile
  const int ar = t >> 3;
  const int aj = t & 7;
  const float* xbase = X + (row0 + ar) * D_IN + (aj << 3);
  unsigned short* awr = lds_A + (ar << 6) + ((aj ^ (ar & 7)) << 3);

  float4 xf[8];        // one A-group of X in flight (32 VGPR)
  v4f acc1[8];         // [rg*4+j]: rows rg*16.. x cols w*64+j*16..
#pragma unroll
  for (int j = 0; j < 8; ++j) acc1[j] = (v4f)(0.0f);

#define STAGEB(T) do {                                                    \
    _Pragma("unroll")                                                     \
    for (int s_ = 0; s_ < 8; ++s_)                                        \
      async16(projT + bsrc0 + s_ * (8 * D_IN) + (T) * BK,                 \
              lds_B + (((((T) & 1) << 2) | w) << 12) + (s_ << 9));        \
  } while (0)

#define XLD_GROUP(g) do {                                                 \
    _Pragma("unroll")                                                     \
    for (int i_ = 0; i_ < 4; ++i_) {                                      \
      xf[2*i_]   = *(const float4*)(xbase + (((g)*4 + i_) << 6));         \
      xf[2*i_+1] = *(const float4*)(xbase + (((g)*4 + i_) << 6) + 4);     \
    }                                                                     \
  } while (0)

#define CVTWRA() do {                                                    \
    _Pragma("unroll")                                                    \
    for (int i_ = 0; i_ < 4; ++i_) {                                     \
      const float4 f0_ = xf[2*i_], f1_ = xf[2*i_+1];                     \
      v8s o_;                                                            \
      o_[0] = f2bf(f0_.x); o_[1] = f2bf(f0_.y);                          \
      o_[2] = f2bf(f0_.z); o_[3] = f2bf(f0_.w);                          \
      o_[4] = f2bf(f1_.x); o_[5] = f2bf(f1_.y);                          \
      o_[6] = f2bf(f1_.z); o_[7] = f2bf(f1_.w);                          \
      *(v8s*)(awr + (i_ << 11)) = o_;                                    \
    }                                                                    \
  } while (0)

#define MFMA_ __builtin_amdgcn_mfma_f32_16x16x32_bf16
#define COMPUTE(T) do {                                                  \
    const unsigned short* Ab_ = lds_A + (((T) & 3) << 11);               \
    const unsigned short* Bq_ = lds_B + (((((T) & 1) << 2) | w) << 12);  \
    _Pragma("unroll")                                                    \
    for (int kk_ = 0; kk_ < 2; ++kk_) {                                  \
      const int po_ = (((kk_ << 2) + q) ^ (lc & 7)) << 3;                \
      v8s a0_ = *(const v8s*)(Ab_ + (lc << 6) + po_);                    \
      v8s a1_ = *(const v8s*)(Ab_ + ((16 + lc) << 6) + po_);             \
      v8s b0_ = *(const v8s*)(Bq_ + (lc << 6) + po_);                    \
      v8s b1_ = *(const v8s*)(Bq_ + 1024 + (lc << 6) + po_);             \
      v8s b2_ = *(const v8s*)(Bq_ + 2048 + (lc << 6) + po_);             \
      v8s b3_ = *(const v8s*)(Bq_ + 3072 + (lc << 6) + po_);             \
      acc1[0] = MFMA_(a0_, b0_, acc1[0], 0, 0, 0);                       \
      acc1[1] = MFMA_(a0_, b1_, acc1[1], 0, 0, 0);                       \
      acc1[2] = MFMA_(a0_, b2_, acc1[2], 0, 0, 0);                       \
      acc1[3] = MFMA_(a0_, b3_, acc1[3], 0, 0, 0);                       \
      acc1[4] = MFMA_(a1_, b0_, acc1[4], 0, 0, 0);                       \
      acc1[5] = MFMA_(a1_, b1_, acc1[5], 0, 0, 0);                       \
      acc1[6] = MFMA_(a1_, b2_, acc1[6], 0, 0, 0);                       \
      acc1[7] = MFMA_(a1_, b3_, acc1[7], 0, 0, 0);                       \
    }                                                                    \
  } while (0)

// wave-local tile: wait B(T) landed (VM = #newer in-flight), compute,
// ensure reads drained (lgkm), then reuse the buffer for B(T+2).
#define TILE(T, VM) do {                                                 \
    asm volatile("s_waitcnt vmcnt(" #VM ")" ::: "memory");               \
    __builtin_amdgcn_sched_barrier(0);                                   \
    COMPUTE(T);                                                          \
    asm volatile("s_waitcnt lgkmcnt(0)" ::: "memory");                   \
    __builtin_amdgcn_sched_barrier(0);                                   \
    if ((T) + 2 <= 15) STAGEB((T) + 2);                                  \
  } while (0)

  // ---- prologue: X(g0), B(0), B(1), X(g1); cvt+write A(g0); one barrier ----
  XLD_GROUP(0);
  STAGEB(0);
  STAGEB(1);
  XLD_GROUP(1);
  CVTWRA();                 // compiler auto-waits the xf(g0) regs (vmcnt>=24)
  GBAR();                   // A(g0) visible to all waves

  // ---- barrier-free k-loop (A-group handoffs only) ----
  TILE(0, 16); TILE(1, 16); TILE(2, 8); TILE(3, 8);
  GBAR(); CVTWRA(); GBAR(); XLD_GROUP(2);
  TILE(4, 16); TILE(5, 16); TILE(6, 8); TILE(7, 8);
  GBAR(); CVTWRA(); GBAR(); XLD_GROUP(3);
  TILE(8, 16); TILE(9, 16); TILE(10, 8); TILE(11, 8);
  GBAR(); CVTWRA(); GBAR();
  TILE(12, 8); TILE(13, 8); TILE(14, 8); TILE(15, 0);
  GBAR();                   // all waves done with lds_B before Z aliases it

  // ---- GEMM2 proto loads issued now: latency hides under the Z phase ----
  v8s pb[8];
  {
    const unsigned short* prow = protoB + ((w << 4) + lc) * D_PROJ + (q << 3);
#pragma unroll
    for (int kk = 0; kk < 8; ++kk)
      pb[kk] = *(const v8s*)(prow + (kk << 5));
  }

  // ---- Zc = Zraw - mu_p -> Z (aliases lds_B buf0) + fp32 row norms ----
  unsigned short* lds_Z = lds_B;      // 32 x 264 shorts = 16.5 KB < 32 KB buf0
  float mu[4];
#pragma unroll
  for (int j = 0; j < 4; ++j) mu[j] = mu_p[(w << 6) + (j << 4) + lc];
#pragma unroll
  for (int rg = 0; rg < 2; ++rg) {
#pragma unroll
    for (int r = 0; r < 4; ++r) {
      const int row = (rg << 4) + (q << 2) + r;
      float s2 = 0.0f;
#pragma unroll
      for (int j = 0; j < 4; ++j) {
        const float v = acc1[rg * 4 + j][r] - mu[j];
        s2 += v * v;
        lds_Z[row * Z_STRIDE + (w << 6) + (j << 4) + lc] = f2bf(v);
      }
      s2 += __shfl_xor(s2, 1);
      s2 += __shfl_xor(s2, 2);
      s2 += __shfl_xor(s2, 4);
      s2 += __shfl_xor(s2, 8);
      if (lc == 0) lds_part[w * BM + row] = s2;
    }
  }
  __syncthreads();
  if (t < BM) {
    const float n2 = lds_part[t] + lds_part[BM + t] +
                     lds_part[2 * BM + t] + lds_part[3 * BM + t];
    const float nrm = sqrtf(n2);
    const float inv = 1.0f / fmaxf(nrm, 1e-12f);   // torch/jax normalize eps
    lds_inv[t] = inv;
    lds_z2[t]  = n2 * inv * inv;                   // == 1 unless degenerate
  }
  __syncthreads();

  // ---- GEMM2: dot(Zc, proto_c); wave w: 32 rows x protos w*16..+15 ----
  v4f acc2[2] = { (v4f)(0.0f), (v4f)(0.0f) };
#pragma unroll
  for (int kk = 0; kk < 8; ++kk) {
#pragma unroll
    for (int sr = 0; sr < 2; ++sr) {
      v8s za = *(const v8s*)(lds_Z + ((sr << 4) + lc) * Z_STRIDE +
                             (kk << 5) + (q << 3));
      acc2[sr] = MFMA_(za, pb[kk], acc2[sr], 0, 0, 0);
    }
  }

  // ---- epilogue: d^2 = ||Z||^2 + ||p||^2 - 2*dot*inv ; score = -sqrt(d^2) ----
  const int c  = (w << 4) + lc;
  const float pn = pnorm2[c];
#pragma unroll
  for (int sr = 0; sr < 2; ++sr) {
#pragma unroll
    for (int r = 0; r < 4; ++r) {
      const int row = (sr << 4) + (q << 2) + r;
      const float inv = lds_inv[row];
      const float d2  = lds_z2[row] + pn - 2.0f * acc2[sr][r] * inv;
      out[(row0 + row) * N_C + c] = -sqrtf(fmaxf(d2, 0.0f));
    }
  }
}

extern "C" void kernel_launch(void* const* d_in, const int* in_sizes, int n_in,
                              void* d_out, int out_size, void* d_ws, size_t ws_size,
                              hipStream_t stream) {
  const float* X      = (const float*)d_in[0];
  const float* protos = (const float*)d_in[1];
  const float* mean   = (const float*)d_in[2];
  const float* proj   = (const float*)d_in[3];
  float* out = (float*)d_out;

  unsigned short* projT  = (unsigned short*)d_ws;          // 256*1024 bf16 = 512 KB
  unsigned short* protoB = projT + D_PROJ * D_IN;          // 64*256  bf16 = 32 KB
  float*          pn2    = (float*)(protoB + N_C * D_PROJ);// 64 fp32
  float*          mup    = pn2 + N_C;                      // 256 fp32

  prep_kernel<<<96, 256, 0, stream>>>(proj, protos, mean, projT, protoB, pn2, mup);
  protonet_main<<<N_ROWS / BM, 256, 0, stream>>>(X, projT, protoB, pn2, mup, out);
}